// Round 15
// baseline (34.188 us; speedup 1.0000x reference)
//
#include <hip/hip_runtime.h>
#include <math.h>

#define H 2048
#define L 350
#define NB 1024
#define NREP 16
#define MAGIC 0x7FC0FFEEu
#define BOUND 65536

// block roles
#define CTX_B0 88      // 64 ctx blocks: 88..151 (watchers = 88..119)
#define GHB_B0 152     // 872 gh blocks: 152..1023
#define GH_TAIL 5792   // gh rows 5792..6143 on logit blocks (88*4 = 352)

// ws float offsets
#define OFF_GH   512
#define OFF_CTXR 8192        // 16 x 2048
#define OFF_GR   40960       // 16 x 2048
#define OFF_MK   73728       // uint marker area

// marker slots (uints, stride 16 = 64B)
#define SLOTA 0               // 88   logits
#define SLOTB (88*16)         // 64   ctx
#define SLOTC (SLOTB+64*16)   // 960  gh (872 main + 88 tail)
#define SLOTG (SLOTC+960*16)  // 1024 combine
#define SUPC  (SLOTG+1024*16) // 32
#define SUPG  (SUPC+32*16)    // 32

#define VMCNT0() asm volatile("s_waitcnt vmcnt(0)" ::: "memory")

__device__ __forceinline__ float cload(const float* p) {
    return __hip_atomic_load(p, __ATOMIC_RELAXED, __HIP_MEMORY_SCOPE_AGENT);
}
__device__ __forceinline__ void cstore(float* p, float v) {
    __hip_atomic_store(p, v, __ATOMIC_RELAXED, __HIP_MEMORY_SCOPE_AGENT);
}
__device__ __forceinline__ unsigned long long cload64(const unsigned long long* p) {
    return __hip_atomic_load(p, __ATOMIC_RELAXED, __HIP_MEMORY_SCOPE_AGENT);
}
__device__ __forceinline__ void postmk(unsigned* p) {
    __hip_atomic_store(p, MAGIC, __ATOMIC_RELAXED, __HIP_MEMORY_SCOPE_SYSTEM);
}
__device__ __forceinline__ unsigned peekmk(const unsigned* p) {
    return __hip_atomic_load(p, __ATOMIC_RELAXED, __HIP_MEMORY_SCOPE_SYSTEM);
}
__device__ __forceinline__ void pollone(const unsigned* p) {
    for (int it = 0; it < BOUND; ++it) {
        if (peekmk(p) == MAGIC) break;
        __builtin_amdgcn_s_sleep(8);
    }
}
__device__ __forceinline__ void waitslots(const unsigned* base, int n) {
    for (int s = threadIdx.x; s < n; s += 512) pollone(&base[s * 16]);
    __syncthreads();
}

__device__ __forceinline__ float dot4(float4 a, float4 b, float acc) {
    acc = fmaf(a.x, b.x, acc);
    acc = fmaf(a.y, b.y, acc);
    acc = fmaf(a.z, b.z, acc);
    acc = fmaf(a.w, b.w, acc);
    return acc;
}
__device__ __forceinline__ float wsum(float v) {
    #pragma unroll
    for (int m = 1; m < 64; m <<= 1) v += __shfl_xor(v, m, 64);
    return v;
}
__device__ __forceinline__ float wmax(float v) {
    #pragma unroll
    for (int m = 1; m < 64; m <<= 1) v = fmaxf(v, __shfl_xor(v, m, 64));
    return v;
}

__device__ __forceinline__ void gh_row(int row, int lane,
    const float4* h4, const float* w_hh, const float* b_hh, float* gh)
{
    const float4* Wr = reinterpret_cast<const float4*>(w_hh + (size_t)row * H);
    float a0 = 0.f, a1 = 0.f, a2 = 0.f, a3 = 0.f;
    #pragma unroll
    for (int k = 0; k < 8; k += 4) {
        a0 = dot4(Wr[lane + (k + 0) * 64], h4[lane + (k + 0) * 64], a0);
        a1 = dot4(Wr[lane + (k + 1) * 64], h4[lane + (k + 1) * 64], a1);
        a2 = dot4(Wr[lane + (k + 2) * 64], h4[lane + (k + 2) * 64], a2);
        a3 = dot4(Wr[lane + (k + 3) * 64], h4[lane + (k + 3) * 64], a3);
    }
    const float acc = wsum((a0 + a1) + (a2 + a3));
    if (lane == 0) cstore(&gh[row], acc + b_hh[row]);
}

__global__ __launch_bounds__(512, 8) void fused_decoder(
    const float* __restrict__ input, const float* __restrict__ hidden,
    const float* __restrict__ enc,
    const float* __restrict__ attn_W, const float* __restrict__ attn_b,
    const float* __restrict__ comb_W, const float* __restrict__ comb_b,
    const float* __restrict__ w_ih, const float* __restrict__ w_hh,
    const float* __restrict__ b_ih, const float* __restrict__ b_hh,
    float* __restrict__ out, float* __restrict__ ws)
{
    __shared__ __align__(16) float sh[2048];
    __shared__ float smax[8], ssum[8];
    __shared__ float part[16][32];
    __shared__ float red[2][4];
    __shared__ float p3[2][4][3];

    float* logits = ws;
    float* gh     = ws + OFF_GH;
    float* ctxrep = ws + OFF_CTXR;
    float* grep   = ws + OFF_GR;
    unsigned* mk  = (unsigned*)(ws + OFF_MK);

    const int b = blockIdx.x, tid = threadIdx.x;
    const int wv = tid >> 6, lane = tid & 63;
    const float4* x4 = reinterpret_cast<const float4*>(input);
    const float4* h4 = reinterpret_cast<const float4*>(hidden);

    // ======================= phase 1 =======================
    if (b < CTX_B0) {
        // waves 0-3: logit rows b*4+wv (16KB); waves 4-7: tail gh rows (8KB)
        if (wv < 4) {
            const int r = b * 4 + wv;
            if (r < L) {
                const float4* Wr = reinterpret_cast<const float4*>(attn_W + (size_t)r * (2 * H));
                float a0 = 0.f, a1 = 0.f, a2 = 0.f, a3 = 0.f;
                #pragma unroll
                for (int k = 0; k < 8; k += 4) {
                    a0 = dot4(Wr[lane + (k+0)*64], x4[lane + (k+0)*64], a0);
                    a1 = dot4(Wr[lane + (k+1)*64], x4[lane + (k+1)*64], a1);
                    a2 = dot4(Wr[lane + (k+2)*64], x4[lane + (k+2)*64], a2);
                    a3 = dot4(Wr[lane + (k+3)*64], x4[lane + (k+3)*64], a3);
                }
                #pragma unroll
                for (int k = 0; k < 8; k += 4) {
                    a0 = dot4(Wr[512 + lane + (k+0)*64], h4[lane + (k+0)*64], a0);
                    a1 = dot4(Wr[512 + lane + (k+1)*64], h4[lane + (k+1)*64], a1);
                    a2 = dot4(Wr[512 + lane + (k+2)*64], h4[lane + (k+2)*64], a2);
                    a3 = dot4(Wr[512 + lane + (k+3)*64], h4[lane + (k+3)*64], a3);
                }
                const float acc = wsum((a0 + a1) + (a2 + a3));
                if (lane == 0) cstore(&logits[r], acc + attn_b[r]);
            }
        } else {
            gh_row(GH_TAIL + b * 4 + (wv - 4), lane, h4, w_hh, b_hh, gh);
        }
        VMCNT0();
        __syncthreads();
        if (tid == 0) { postmk(&mk[SLOTA + b * 16]); postmk(&mk[SLOTC + (872 + b) * 16]); }
    } else if (b < GHB_B0) {
        // ---- ctx blocks: wait logits, softmax (512-thr), 32 ctx cols ----
        const int cb = b - CTX_B0;
        waitslots(&mk[SLOTA], 88);
        float v0 = (tid < L) ? cload(&logits[tid]) : -INFINITY;
        float m = wmax(v0);
        if (lane == 0) smax[wv] = m;
        __syncthreads();
        m = fmaxf(fmaxf(fmaxf(smax[0], smax[1]), fmaxf(smax[2], smax[3])),
                  fmaxf(fmaxf(smax[4], smax[5]), fmaxf(smax[6], smax[7])));
        float e0 = (tid < L) ? expf(v0 - m) : 0.f;
        float s = wsum(e0);
        if (lane == 0) ssum[wv] = s;
        __syncthreads();
        const float inv = 1.f / (((ssum[0] + ssum[1]) + (ssum[2] + ssum[3]))
                               + ((ssum[4] + ssum[5]) + (ssum[6] + ssum[7])));
        if (tid < L) sh[tid] = e0 * inv;
        if (cb == 0 && tid < L) out[2 * H + tid] = e0 * inv;
        __syncthreads();
        // ctx: 32 cols, 16-way row split, 2-deep ILP
        const int col_l = tid & 31, k = tid >> 5;
        const float* ec = enc + cb * 32 + col_l;
        float a0 = 0.f, a1 = 0.f;
        int j = k;
        for (; j + 16 < L; j += 32) {
            a0 = fmaf(sh[j],      ec[(size_t)j * H],        a0);
            a1 = fmaf(sh[j + 16], ec[(size_t)(j + 16) * H], a1);
        }
        for (; j < L; j += 16) a0 = fmaf(sh[j], ec[(size_t)j * H], a0);
        part[k][col_l] = a0 + a1;
        __syncthreads();
        if (tid < 32) {
            float acc = 0.f;
            #pragma unroll
            for (int kk = 0; kk < 16; ++kk) acc += part[kk][tid];
            #pragma unroll
            for (int rp = 0; rp < NREP; ++rp)
                cstore(&ctxrep[rp * 2048 + cb * 32 + tid], acc);
        }
        VMCNT0();
        __syncthreads();
        if (tid == 0) postmk(&mk[SLOTB + cb * 16]);
    } else {
        // ---- gh main blocks: m<560 -> 7 rows, else 6 rows; 1 row/wave ----
        const int m = b - GHB_B0;
        const int start = (m < 560) ? m * 7 : 3920 + (m - 560) * 6;
        const int count = (m < 560) ? 7 : 6;
        if (wv < count) gh_row(start + wv, lane, h4, w_hh, b_hh, gh);
        VMCNT0();
        __syncthreads();
        if (tid == 0) postmk(&mk[SLOTC + m * 16]);
    }

    // ======================= phase 2: combine (2 rows, two 256-thr teams) ==
    waitslots(&mk[SLOTB], 64);
    {
        unsigned long long* sh64 = reinterpret_cast<unsigned long long*>(sh);
        const unsigned long long* c64 =
            reinterpret_cast<const unsigned long long*>(ctxrep + (b & (NREP - 1)) * 2048);
        for (int i = tid; i < H / 2; i += 512) sh64[i] = cload64(&c64[i]);
    }
    __syncthreads();
    {
        const int team = tid >> 8, ttid = tid & 255, twv = (tid >> 6) & 3;
        const float4* c4 = reinterpret_cast<const float4*>(sh);
        const int r = b * 2 + team;
        const float4* Wr = reinterpret_cast<const float4*>(comb_W + (size_t)r * (2 * H));
        float a0 = dot4(Wr[ttid],       x4[ttid],       0.f);
        float a1 = dot4(Wr[ttid + 256], x4[ttid + 256], 0.f);
        float a2 = dot4(Wr[ttid + 512], c4[ttid],       0.f);
        float a3 = dot4(Wr[ttid + 768], c4[ttid + 256], 0.f);
        const float acc = wsum((a0 + a1) + (a2 + a3));
        if (lane == 0) red[team][twv] = acc;
        __syncthreads();
        if (ttid == 0) {
            const float gval = fmaxf(red[team][0] + red[team][1] + red[team][2]
                                     + red[team][3] + comb_b[r], 0.f);
            #pragma unroll
            for (int rp = 0; rp < NREP; ++rp) cstore(&grep[rp * 2048 + r], gval);
        }
        __syncthreads();
    }
    VMCNT0();
    if (tid == 0) postmk(&mk[SLOTG + b * 16]);

    // ======================= watchers: aggregate SLOTC + SLOTG =============
    if (b >= CTX_B0 && b < CTX_B0 + 32) {
        const int w = b - CTX_B0;
        if (tid < 30) pollone(&mk[SLOTC + (w * 30 + tid) * 16]);
        else if (tid >= 64 && tid < 96) pollone(&mk[SLOTG + (w * 32 + tid - 64) * 16]);
        __syncthreads();
        if (tid == 0) { postmk(&mk[SUPC + w * 16]); postmk(&mk[SUPG + w * 16]); }
    }

    // ======================= phase 3: GRU (2 cols, two teams) ==============
    if (tid < 32) pollone(&mk[SUPC + tid * 16]);
    else if (tid >= 64 && tid < 96) pollone(&mk[SUPG + (tid - 64) * 16]);
    __syncthreads();
    {
        unsigned long long* sh64 = reinterpret_cast<unsigned long long*>(sh);
        const unsigned long long* g64 =
            reinterpret_cast<const unsigned long long*>(grep + (b & (NREP - 1)) * 2048);
        for (int i = tid; i < H / 2; i += 512) sh64[i] = cload64(&g64[i]);
    }
    __syncthreads();
    {
        const int team = tid >> 8, ttid = tid & 255, twv = (tid >> 6) & 3;
        const float4* g4 = reinterpret_cast<const float4*>(sh);
        const int col = b * 2 + team;
        const float4* W0 = reinterpret_cast<const float4*>(w_ih + (size_t)col * H);
        const float4* W1 = reinterpret_cast<const float4*>(w_ih + (size_t)(col + H) * H);
        const float4* W2 = reinterpret_cast<const float4*>(w_ih + (size_t)(col + 2 * H) * H);
        const float4 gv0 = g4[ttid], gv1 = g4[ttid + 256];
        float ar = dot4(W0[ttid], gv0, 0.f); ar = dot4(W0[ttid + 256], gv1, ar);
        float az = dot4(W1[ttid], gv0, 0.f); az = dot4(W1[ttid + 256], gv1, az);
        float an = dot4(W2[ttid], gv0, 0.f); an = dot4(W2[ttid + 256], gv1, an);
        ar = wsum(ar); az = wsum(az); an = wsum(an);
        if (lane == 0) { p3[team][twv][0] = ar; p3[team][twv][1] = az; p3[team][twv][2] = an; }
        __syncthreads();
        if (ttid == 0) {
            const float ir  = p3[team][0][0] + p3[team][1][0] + p3[team][2][0] + p3[team][3][0] + b_ih[col];
            const float iz  = p3[team][0][1] + p3[team][1][1] + p3[team][2][1] + p3[team][3][1] + b_ih[col + H];
            const float in_ = p3[team][0][2] + p3[team][1][2] + p3[team][2][2] + p3[team][3][2] + b_ih[col + 2 * H];
            const float r = 1.f / (1.f + expf(-(ir + cload(&gh[col]))));
            const float z = 1.f / (1.f + expf(-(iz + cload(&gh[col + H]))));
            const float n = tanhf(in_ + r * cload(&gh[col + 2 * H]));
            const float hnew = (1.f - z) * n + z * hidden[col];
            out[col] = hnew;
            out[H + col] = hnew;
        }
    }
}

extern "C" void kernel_launch(void* const* d_in, const int* in_sizes, int n_in,
                              void* d_out, int out_size, void* d_ws, size_t ws_size,
                              hipStream_t stream)
{
    const float* input  = (const float*)d_in[0];
    const float* hidden = (const float*)d_in[1];
    const float* enc    = (const float*)d_in[2];
    const float* attn_W = (const float*)d_in[3];
    const float* attn_b = (const float*)d_in[4];
    const float* comb_W = (const float*)d_in[5];
    const float* comb_b = (const float*)d_in[6];
    const float* w_ih   = (const float*)d_in[7];
    const float* w_hh   = (const float*)d_in[8];
    const float* b_ih   = (const float*)d_in[9];
    const float* b_hh   = (const float*)d_in[10];
    float* out = (float*)d_out;
    float* ws  = (float*)d_ws;

    fused_decoder<<<NB, 512, 0, stream>>>(
        input, hidden, enc, attn_W, attn_b, comb_W, comb_b,
        w_ih, w_hh, b_ih, b_hh, out, ws);
}

// Round 16
// 33.786 us; speedup vs baseline: 1.0119x; 1.0119x over previous
//
#include <hip/hip_runtime.h>
#include <math.h>

#define H 2048
#define L 350
#define NB 1024
#define NREP 8
#define MAGIC 0x7FC0FFEEu
#define BOUND 65536

// block roles
#define CTX_B0 88      // 64 ctx blocks: 88..151 (watchers = 88..119)
#define GHB_B0 152     // 872 gh blocks: 152..1023

// ws float offsets
#define OFF_GH   512
#define OFF_CTXR 8192        // NREP x 2048
#define OFF_GR   40960       // NREP x 2048
#define OFF_MK   73728       // uint marker area

// marker slots (uints, stride 16 = 64B)
#define SLOTA 0               // 88   logits
#define SLOTB (88*16)         // 64   ctx
#define SLOTC (SLOTB+64*16)   // 912  gh (872 main + 40 tail)
#define SLOTG (SLOTC+912*16)  // 1024 combine
#define SUPC  (SLOTG+1024*16) // 32
#define SUPG  (SUPC+32*16)    // 32

#define VMCNT0() asm volatile("s_waitcnt vmcnt(0)" ::: "memory")

__device__ __forceinline__ float cload(const float* p) {
    return __hip_atomic_load(p, __ATOMIC_RELAXED, __HIP_MEMORY_SCOPE_AGENT);
}
__device__ __forceinline__ void cstore(float* p, float v) {
    __hip_atomic_store(p, v, __ATOMIC_RELAXED, __HIP_MEMORY_SCOPE_AGENT);
}
__device__ __forceinline__ unsigned long long cload64(const unsigned long long* p) {
    return __hip_atomic_load(p, __ATOMIC_RELAXED, __HIP_MEMORY_SCOPE_AGENT);
}
__device__ __forceinline__ float4 cload128(const float* p) {
    const unsigned long long* q = reinterpret_cast<const unsigned long long*>(p);
    const unsigned long long a = cload64(&q[0]);
    const unsigned long long b = cload64(&q[1]);
    float4 r;
    r.x = __uint_as_float((unsigned)a);  r.y = __uint_as_float((unsigned)(a >> 32));
    r.z = __uint_as_float((unsigned)b);  r.w = __uint_as_float((unsigned)(b >> 32));
    return r;
}
__device__ __forceinline__ void postmk(unsigned* p) {
    __hip_atomic_store(p, MAGIC, __ATOMIC_RELAXED, __HIP_MEMORY_SCOPE_SYSTEM);
}
__device__ __forceinline__ unsigned peekmk(const unsigned* p) {
    return __hip_atomic_load(p, __ATOMIC_RELAXED, __HIP_MEMORY_SCOPE_SYSTEM);
}
__device__ __forceinline__ void pollone(const unsigned* p) {
    for (int it = 0; it < BOUND; ++it) {
        if (peekmk(p) == MAGIC) break;
        __builtin_amdgcn_s_sleep(8);
    }
}
__device__ __forceinline__ void waitslots(const unsigned* base, int n) {
    for (int s = threadIdx.x; s < n; s += 256) pollone(&base[s * 16]);
    __syncthreads();
}

__device__ __forceinline__ float dot4(float4 a, float4 b, float acc) {
    acc = fmaf(a.x, b.x, acc);
    acc = fmaf(a.y, b.y, acc);
    acc = fmaf(a.z, b.z, acc);
    acc = fmaf(a.w, b.w, acc);
    return acc;
}
__device__ __forceinline__ float wsum(float v) {
    #pragma unroll
    for (int m = 1; m < 64; m <<= 1) v += __shfl_xor(v, m, 64);
    return v;
}
__device__ __forceinline__ float wmax(float v) {
    #pragma unroll
    for (int m = 1; m < 64; m <<= 1) v = fmaxf(v, __shfl_xor(v, m, 64));
    return v;
}

__device__ __forceinline__ void gh_row(int row, int lane,
    const float4* h4, const float* w_hh, const float* b_hh, float* gh)
{
    const float4* Wr = reinterpret_cast<const float4*>(w_hh + (size_t)row * H);
    float a0 = 0.f, a1 = 0.f, a2 = 0.f, a3 = 0.f;
    #pragma unroll
    for (int k = 0; k < 8; k += 4) {
        a0 = dot4(Wr[lane + (k + 0) * 64], h4[lane + (k + 0) * 64], a0);
        a1 = dot4(Wr[lane + (k + 1) * 64], h4[lane + (k + 1) * 64], a1);
        a2 = dot4(Wr[lane + (k + 2) * 64], h4[lane + (k + 2) * 64], a2);
        a3 = dot4(Wr[lane + (k + 3) * 64], h4[lane + (k + 3) * 64], a3);
    }
    const float acc = wsum((a0 + a1) + (a2 + a3));
    if (lane == 0) cstore(&gh[row], acc + b_hh[row]);
}

__global__ __launch_bounds__(256, 4) void fused_decoder(
    const float* __restrict__ input, const float* __restrict__ hidden,
    const float* __restrict__ enc,
    const float* __restrict__ attn_W, const float* __restrict__ attn_b,
    const float* __restrict__ comb_W, const float* __restrict__ comb_b,
    const float* __restrict__ w_ih, const float* __restrict__ w_hh,
    const float* __restrict__ b_ih, const float* __restrict__ b_hh,
    float* __restrict__ out, float* __restrict__ ws)
{
    __shared__ __align__(16) float sh[2048];
    __shared__ float smax[4], ssum[4];
    __shared__ float part[8][32];
    __shared__ float red[4];
    __shared__ float p3[4][3];

    float* logits = ws;
    float* gh     = ws + OFF_GH;
    float* ctxrep = ws + OFF_CTXR;
    float* grep   = ws + OFF_GR;
    unsigned* mk  = (unsigned*)(ws + OFF_MK);

    const int b = blockIdx.x, tid = threadIdx.x;
    const int wv = tid >> 6, lane = tid & 63;
    const float4* x4 = reinterpret_cast<const float4*>(input);
    const float4* h4 = reinterpret_cast<const float4*>(hidden);

    // ======================= phase 1 (identical to R14) ====================
    if (b < CTX_B0) {
        const int r = b * 4 + wv;
        if (r < L) {
            const float4* Wr = reinterpret_cast<const float4*>(attn_W + (size_t)r * (2 * H));
            float a0 = 0.f, a1 = 0.f, a2 = 0.f, a3 = 0.f;
            #pragma unroll
            for (int k = 0; k < 8; k += 4) {
                a0 = dot4(Wr[lane + (k+0)*64], x4[lane + (k+0)*64], a0);
                a1 = dot4(Wr[lane + (k+1)*64], x4[lane + (k+1)*64], a1);
                a2 = dot4(Wr[lane + (k+2)*64], x4[lane + (k+2)*64], a2);
                a3 = dot4(Wr[lane + (k+3)*64], x4[lane + (k+3)*64], a3);
            }
            #pragma unroll
            for (int k = 0; k < 8; k += 4) {
                a0 = dot4(Wr[512 + lane + (k+0)*64], h4[lane + (k+0)*64], a0);
                a1 = dot4(Wr[512 + lane + (k+1)*64], h4[lane + (k+1)*64], a1);
                a2 = dot4(Wr[512 + lane + (k+2)*64], h4[lane + (k+2)*64], a2);
                a3 = dot4(Wr[512 + lane + (k+3)*64], h4[lane + (k+3)*64], a3);
            }
            const float acc = wsum((a0 + a1) + (a2 + a3));
            if (lane == 0) cstore(&logits[r], acc + attn_b[r]);
        }
        VMCNT0();
        __syncthreads();
        if (tid == 0) postmk(&mk[SLOTA + b * 16]);
        if (b < 40) {
            if (wv == 0) gh_row(6104 + b, lane, h4, w_hh, b_hh, gh);
            VMCNT0();
            __syncthreads();
            if (tid == 0) postmk(&mk[SLOTC + (872 + b) * 16]);
        }
    } else if (b < GHB_B0) {
        const int cb = b - CTX_B0;
        waitslots(&mk[SLOTA], 88);
        float v0 = (tid < L) ? cload(&logits[tid]) : -INFINITY;
        float v1 = (tid + 256 < L) ? cload(&logits[tid + 256]) : -INFINITY;
        float m = wmax(fmaxf(v0, v1));
        if (lane == 0) smax[wv] = m;
        __syncthreads();
        m = fmaxf(fmaxf(smax[0], smax[1]), fmaxf(smax[2], smax[3]));
        float e0 = (tid < L) ? expf(v0 - m) : 0.f;
        float e1 = (tid + 256 < L) ? expf(v1 - m) : 0.f;
        float s = wsum(e0 + e1);
        if (lane == 0) ssum[wv] = s;
        __syncthreads();
        const float inv = 1.f / (ssum[0] + ssum[1] + ssum[2] + ssum[3]);
        if (tid < L) sh[tid] = e0 * inv;
        if (tid + 256 < L) sh[tid + 256] = e1 * inv;
        if (cb == 0) {
            if (tid < L) out[2 * H + tid] = e0 * inv;
            if (tid + 256 < L) out[2 * H + tid + 256] = e1 * inv;
        }
        __syncthreads();
        const int col_l = tid & 31, k = tid >> 5;
        const float* ec = enc + cb * 32 + col_l;
        float a0 = 0.f, a1 = 0.f, a2 = 0.f, a3 = 0.f;
        int j = k;
        for (; j + 24 < L; j += 32) {
            a0 = fmaf(sh[j],      ec[(size_t)j * H],        a0);
            a1 = fmaf(sh[j + 8],  ec[(size_t)(j + 8) * H],  a1);
            a2 = fmaf(sh[j + 16], ec[(size_t)(j + 16) * H], a2);
            a3 = fmaf(sh[j + 24], ec[(size_t)(j + 24) * H], a3);
        }
        for (; j < L; j += 8) a0 = fmaf(sh[j], ec[(size_t)j * H], a0);
        part[k][col_l] = (a0 + a1) + (a2 + a3);
        __syncthreads();
        if (tid < 32) {
            const float acc = part[0][tid] + part[1][tid] + part[2][tid] + part[3][tid]
                            + part[4][tid] + part[5][tid] + part[6][tid] + part[7][tid];
            #pragma unroll
            for (int rp = 0; rp < NREP; ++rp)
                cstore(&ctxrep[rp * 2048 + cb * 32 + tid], acc);
        }
        VMCNT0();
        __syncthreads();
        if (tid == 0) postmk(&mk[SLOTB + cb * 16]);
    } else {
        const int m = b - GHB_B0;
        #pragma unroll
        for (int j = 0; j < 7; ++j)
            if ((j & 3) == wv) gh_row(m * 7 + j, lane, h4, w_hh, b_hh, gh);
        VMCNT0();
        __syncthreads();
        if (tid == 0) postmk(&mk[SLOTC + m * 16]);
    }

    // ============== phase 2: combine, direct sc1 operand reads =============
    waitslots(&mk[SLOTB], 64);
    {
        const float* crep = ctxrep + (b & (NREP - 1)) * 2048;
        const float4 xv0 = x4[tid], xv1 = x4[tid + 256];
        const float4 cv0 = cload128(&crep[tid * 4]);
        const float4 cv1 = cload128(&crep[(tid + 256) * 4]);
        #pragma unroll
        for (int rr = 0; rr < 2; ++rr) {
            const int r = b * 2 + rr;
            const float4* Wr = reinterpret_cast<const float4*>(comb_W + (size_t)r * (2 * H));
            float a0 = dot4(Wr[tid],       xv0, 0.f);
            float a1 = dot4(Wr[tid + 256], xv1, 0.f);
            float a2 = dot4(Wr[tid + 512], cv0, 0.f);
            float a3 = dot4(Wr[tid + 768], cv1, 0.f);
            const float acc = wsum((a0 + a1) + (a2 + a3));
            if (lane == 0) red[wv] = acc;
            __syncthreads();
            if (tid == 0) {
                const float gval = fmaxf(red[0] + red[1] + red[2] + red[3] + comb_b[r], 0.f);
                #pragma unroll
                for (int rp = 0; rp < NREP; ++rp) cstore(&grep[rp * 2048 + r], gval);
            }
            __syncthreads();
        }
    }
    VMCNT0();
    if (tid == 0) postmk(&mk[SLOTG + b * 16]);

    // ======================= watchers (identical to R14) ===================
    if (b >= 88 && b < 120) {
        const int w = b - 88;
        const int cfrom = w * 29, cto = (cfrom + 29 < 912) ? cfrom + 29 : 912;
        if (tid < cto - cfrom) pollone(&mk[SLOTC + (cfrom + tid) * 16]);
        else if (tid >= 64 && tid < 96) pollone(&mk[SLOTG + (w * 32 + tid - 64) * 16]);
        __syncthreads();
        if (tid == 0) { postmk(&mk[SUPC + w * 16]); postmk(&mk[SUPG + w * 16]); }
    }

    // ============== phase 3: GRU, direct sc1 operand reads =================
    if (tid < 32) pollone(&mk[SUPC + tid * 16]);
    else if (tid >= 64 && tid < 96) pollone(&mk[SUPG + (tid - 64) * 16]);
    __syncthreads();
    {
        const float* grp = grep + (b & (NREP - 1)) * 2048;
        const float4 gv0 = cload128(&grp[tid * 4]);
        const float4 gv1 = cload128(&grp[(tid + 256) * 4]);
        #pragma unroll
        for (int cc = 0; cc < 2; ++cc) {
            const int col = b * 2 + cc;
            const float4* W0 = reinterpret_cast<const float4*>(w_ih + (size_t)col * H);
            const float4* W1 = reinterpret_cast<const float4*>(w_ih + (size_t)(col + H) * H);
            const float4* W2 = reinterpret_cast<const float4*>(w_ih + (size_t)(col + 2 * H) * H);
            float ar = dot4(W0[tid], gv0, 0.f); ar = dot4(W0[tid + 256], gv1, ar);
            float az = dot4(W1[tid], gv0, 0.f); az = dot4(W1[tid + 256], gv1, az);
            float an = dot4(W2[tid], gv0, 0.f); an = dot4(W2[tid + 256], gv1, an);
            ar = wsum(ar); az = wsum(az); an = wsum(an);
            if (lane == 0) { p3[wv][0] = ar; p3[wv][1] = az; p3[wv][2] = an; }
            __syncthreads();
            if (tid == 0) {
                const float ir  = p3[0][0] + p3[1][0] + p3[2][0] + p3[3][0] + b_ih[col];
                const float iz  = p3[0][1] + p3[1][1] + p3[2][1] + p3[3][1] + b_ih[col + H];
                const float in_ = p3[0][2] + p3[1][2] + p3[2][2] + p3[3][2] + b_ih[col + 2 * H];
                const float r = 1.f / (1.f + expf(-(ir + cload(&gh[col]))));
                const float z = 1.f / (1.f + expf(-(iz + cload(&gh[col + H]))));
                const float n = tanhf(in_ + r * cload(&gh[col + 2 * H]));
                const float hnew = (1.f - z) * n + z * hidden[col];
                out[col] = hnew;
                out[H + col] = hnew;
            }
            __syncthreads();
        }
    }
}

extern "C" void kernel_launch(void* const* d_in, const int* in_sizes, int n_in,
                              void* d_out, int out_size, void* d_ws, size_t ws_size,
                              hipStream_t stream)
{
    const float* input  = (const float*)d_in[0];
    const float* hidden = (const float*)d_in[1];
    const float* enc    = (const float*)d_in[2];
    const float* attn_W = (const float*)d_in[3];
    const float* attn_b = (const float*)d_in[4];
    const float* comb_W = (const float*)d_in[5];
    const float* comb_b = (const float*)d_in[6];
    const float* w_ih   = (const float*)d_in[7];
    const float* w_hh   = (const float*)d_in[8];
    const float* b_ih   = (const float*)d_in[9];
    const float* b_hh   = (const float*)d_in[10];
    float* out = (float*)d_out;
    float* ws  = (float*)d_ws;

    fused_decoder<<<NB, 256, 0, stream>>>(
        input, hidden, enc, attn_W, attn_b, comb_W, comb_b,
        w_ih, w_hh, b_ih, b_hh, out, ws);
}

// Round 17
// 32.231 us; speedup vs baseline: 1.0607x; 1.0482x over previous
//
#include <hip/hip_runtime.h>
#include <math.h>

#define H 2048
#define L 350
#define NB 1024
#define NREP 16
#define MAGIC 0x7FC0FFEEu
#define BOUND 65536

// block roles
#define LOG_B0 0      // 88 logit blocks
#define CTX_B0 88     // 64 ctx blocks (88..151); watchers = 88..119
#define GHB_B0 152    // 872 gh blocks (152..1023)

// ws float offsets
#define OFF_GH   512
#define OFF_CTXR 8192        // 16 x 2048
#define OFF_GR   40960       // 16 x 2048
#define OFF_MK   73728       // uint marker area

// marker slot layout (uints, 16-uint = 64B spacing)
#define SLOTA 0              // 88
#define SLOTB (88*16)        // 64
#define SLOTC (SLOTB+64*16)  // 912 (872 gh blocks + 40 logit blocks)
#define SLOTG (SLOTC+912*16) // 1024
#define SUPC  (SLOTG+1024*16) // 32
#define SUPG  (SUPC+32*16)    // 32

#define VMCNT0() asm volatile("s_waitcnt vmcnt(0)" ::: "memory")

__device__ __forceinline__ float cload(const float* p) {
    return __hip_atomic_load(p, __ATOMIC_RELAXED, __HIP_MEMORY_SCOPE_AGENT);
}
__device__ __forceinline__ void cstore(float* p, float v) {
    __hip_atomic_store(p, v, __ATOMIC_RELAXED, __HIP_MEMORY_SCOPE_AGENT);
}
__device__ __forceinline__ unsigned long long cload64(const unsigned long long* p) {
    return __hip_atomic_load(p, __ATOMIC_RELAXED, __HIP_MEMORY_SCOPE_AGENT);
}
__device__ __forceinline__ void postmk(unsigned* p) {
    __hip_atomic_store(p, MAGIC, __ATOMIC_RELAXED, __HIP_MEMORY_SCOPE_SYSTEM);
}
__device__ __forceinline__ unsigned peekmk(const unsigned* p) {
    return __hip_atomic_load(p, __ATOMIC_RELAXED, __HIP_MEMORY_SCOPE_SYSTEM);
}
// each of first n threads polls one slot; all threads join the barrier
__device__ __forceinline__ void waitslots(const unsigned* base, int n) {
    const int t = threadIdx.x;
    for (int s = t; s < n; s += 256)
        for (int it = 0; it < BOUND; ++it) {
            if (peekmk(&base[s * 16]) == MAGIC) break;
            __builtin_amdgcn_s_sleep(8);
        }
    __syncthreads();
}

__device__ __forceinline__ float dot4(float4 a, float4 b, float acc) {
    acc = fmaf(a.x, b.x, acc);
    acc = fmaf(a.y, b.y, acc);
    acc = fmaf(a.z, b.z, acc);
    acc = fmaf(a.w, b.w, acc);
    return acc;
}
__device__ __forceinline__ float wsum(float v) {
    #pragma unroll
    for (int m = 1; m < 64; m <<= 1) v += __shfl_xor(v, m, 64);
    return v;
}
__device__ __forceinline__ float wmax(float v) {
    #pragma unroll
    for (int m = 1; m < 64; m <<= 1) v = fmaxf(v, __shfl_xor(v, m, 64));
    return v;
}

__device__ __forceinline__ void gh_row(int row, int lane,
    const float4* h4, const float* w_hh, const float* b_hh, float* gh)
{
    const float4* Wr = reinterpret_cast<const float4*>(w_hh + (size_t)row * H);
    float a0 = 0.f, a1 = 0.f, a2 = 0.f, a3 = 0.f;
    #pragma unroll
    for (int k = 0; k < 8; k += 4) {
        a0 = dot4(Wr[lane + (k + 0) * 64], h4[lane + (k + 0) * 64], a0);
        a1 = dot4(Wr[lane + (k + 1) * 64], h4[lane + (k + 1) * 64], a1);
        a2 = dot4(Wr[lane + (k + 2) * 64], h4[lane + (k + 2) * 64], a2);
        a3 = dot4(Wr[lane + (k + 3) * 64], h4[lane + (k + 3) * 64], a3);
    }
    const float acc = wsum((a0 + a1) + (a2 + a3));
    if (lane == 0) cstore(&gh[row], acc + b_hh[row]);
}

__global__ __launch_bounds__(256, 4) void fused_decoder(
    const float* __restrict__ input, const float* __restrict__ hidden,
    const float* __restrict__ enc,
    const float* __restrict__ attn_W, const float* __restrict__ attn_b,
    const float* __restrict__ comb_W, const float* __restrict__ comb_b,
    const float* __restrict__ w_ih, const float* __restrict__ w_hh,
    const float* __restrict__ b_ih, const float* __restrict__ b_hh,
    float* __restrict__ out, float* __restrict__ ws)
{
    __shared__ __align__(16) float sh[2048];
    __shared__ float smax[4], ssum[4];
    __shared__ float part[8][32];
    __shared__ float red[4];
    __shared__ float p3[4][3];

    float* logits = ws;
    float* gh     = ws + OFF_GH;
    float* ctxrep = ws + OFF_CTXR;
    float* grep   = ws + OFF_GR;
    unsigned* mk  = (unsigned*)(ws + OFF_MK);

    const int b = blockIdx.x, tid = threadIdx.x;
    const int wv = tid >> 6, lane = tid & 63;
    const float4* x4 = reinterpret_cast<const float4*>(input);
    const float4* h4 = reinterpret_cast<const float4*>(hidden);

    // ======================= phase 1 =======================
    if (b < CTX_B0) {
        // ---- logits: 1 row/wave, items b*4+wv ----
        const int r = b * 4 + wv;
        if (r < L) {
            const float4* Wr = reinterpret_cast<const float4*>(attn_W + (size_t)r * (2 * H));
            float a0 = 0.f, a1 = 0.f, a2 = 0.f, a3 = 0.f;
            #pragma unroll
            for (int k = 0; k < 8; k += 4) {
                a0 = dot4(Wr[lane + (k+0)*64], x4[lane + (k+0)*64], a0);
                a1 = dot4(Wr[lane + (k+1)*64], x4[lane + (k+1)*64], a1);
                a2 = dot4(Wr[lane + (k+2)*64], x4[lane + (k+2)*64], a2);
                a3 = dot4(Wr[lane + (k+3)*64], x4[lane + (k+3)*64], a3);
            }
            #pragma unroll
            for (int k = 0; k < 8; k += 4) {
                a0 = dot4(Wr[512 + lane + (k+0)*64], h4[lane + (k+0)*64], a0);
                a1 = dot4(Wr[512 + lane + (k+1)*64], h4[lane + (k+1)*64], a1);
                a2 = dot4(Wr[512 + lane + (k+2)*64], h4[lane + (k+2)*64], a2);
                a3 = dot4(Wr[512 + lane + (k+3)*64], h4[lane + (k+3)*64], a3);
            }
            const float acc = wsum((a0 + a1) + (a2 + a3));
            if (lane == 0) cstore(&logits[r], acc + attn_b[r]);
        }
        VMCNT0();
        __syncthreads();
        if (tid == 0) postmk(&mk[SLOTA + b * 16]);
        // tail gh rows 6104..6143 on blocks 0..39 (wave 0 does it)
        if (b < 40) {
            if (wv == 0) gh_row(6104 + b, lane, h4, w_hh, b_hh, gh);
            VMCNT0();
            __syncthreads();
            if (tid == 0) postmk(&mk[SLOTC + (872 + b) * 16]);
        }
    } else if (b < GHB_B0) {
        // ---- ctx blocks: wait logits, softmax, 32 ctx cols ----
        const int cb = b - CTX_B0;
        waitslots(&mk[SLOTA], 88);
        float v0 = (tid < L) ? cload(&logits[tid]) : -INFINITY;
        float v1 = (tid + 256 < L) ? cload(&logits[tid + 256]) : -INFINITY;
        float m = wmax(fmaxf(v0, v1));
        if (lane == 0) smax[wv] = m;
        __syncthreads();
        m = fmaxf(fmaxf(smax[0], smax[1]), fmaxf(smax[2], smax[3]));
        float e0 = (tid < L) ? expf(v0 - m) : 0.f;
        float e1 = (tid + 256 < L) ? expf(v1 - m) : 0.f;
        float s = wsum(e0 + e1);
        if (lane == 0) ssum[wv] = s;
        __syncthreads();
        const float inv = 1.f / (ssum[0] + ssum[1] + ssum[2] + ssum[3]);
        if (tid < L) sh[tid] = e0 * inv;
        if (tid + 256 < L) sh[tid + 256] = e1 * inv;
        if (cb == 0) {
            if (tid < L) out[2 * H + tid] = e0 * inv;
            if (tid + 256 < L) out[2 * H + tid + 256] = e1 * inv;
        }
        __syncthreads();
        const int col_l = tid & 31, k = tid >> 5;
        const float* ec = enc + cb * 32 + col_l;
        float a0 = 0.f, a1 = 0.f, a2 = 0.f, a3 = 0.f;
        int j = k;
        for (; j + 24 < L; j += 32) {
            a0 = fmaf(sh[j],      ec[(size_t)j * H],        a0);
            a1 = fmaf(sh[j + 8],  ec[(size_t)(j + 8) * H],  a1);
            a2 = fmaf(sh[j + 16], ec[(size_t)(j + 16) * H], a2);
            a3 = fmaf(sh[j + 24], ec[(size_t)(j + 24) * H], a3);
        }
        for (; j < L; j += 8) a0 = fmaf(sh[j], ec[(size_t)j * H], a0);
        part[k][col_l] = (a0 + a1) + (a2 + a3);
        __syncthreads();
        if (tid < 32) {
            const float acc = part[0][tid] + part[1][tid] + part[2][tid] + part[3][tid]
                            + part[4][tid] + part[5][tid] + part[6][tid] + part[7][tid];
            #pragma unroll
            for (int rp = 0; rp < NREP; ++rp)
                cstore(&ctxrep[rp * 2048 + cb * 32 + tid], acc);
        }
        VMCNT0();
        __syncthreads();
        if (tid == 0) postmk(&mk[SLOTB + cb * 16]);
    } else {
        // ---- gh blocks: 7 rows each, rows m*7+j ----
        const int m = b - GHB_B0;
        #pragma unroll
        for (int j = 0; j < 7; ++j)
            if ((j & 3) == wv) gh_row(m * 7 + j, lane, h4, w_hh, b_hh, gh);
        VMCNT0();
        __syncthreads();
        if (tid == 0) postmk(&mk[SLOTC + m * 16]);
    }

    // ======================= phase 2: combine (all blocks, 2 rows) =========
    waitslots(&mk[SLOTB], 64);
    {
        unsigned long long* sh64 = reinterpret_cast<unsigned long long*>(sh);
        const unsigned long long* c64 =
            reinterpret_cast<const unsigned long long*>(ctxrep + (b & (NREP - 1)) * 2048);
        for (int i = tid; i < H / 2; i += 256) sh64[i] = cload64(&c64[i]);
    }
    __syncthreads();
    {
        const float4* c4 = reinterpret_cast<const float4*>(sh);
        #pragma unroll
        for (int rr = 0; rr < 2; ++rr) {
            const int r = b * 2 + rr;
            const float4* Wr = reinterpret_cast<const float4*>(comb_W + (size_t)r * (2 * H));
            float a0 = dot4(Wr[tid],       x4[tid],       0.f);
            float a1 = dot4(Wr[tid + 256], x4[tid + 256], 0.f);
            float a2 = dot4(Wr[tid + 512], c4[tid],       0.f);
            float a3 = dot4(Wr[tid + 768], c4[tid + 256], 0.f);
            const float acc = wsum((a0 + a1) + (a2 + a3));
            if (lane == 0) red[wv] = acc;
            __syncthreads();
            if (tid == 0) {
                const float gval = fmaxf(red[0] + red[1] + red[2] + red[3] + comb_b[r], 0.f);
                #pragma unroll
                for (int rp = 0; rp < NREP; ++rp) cstore(&grep[rp * 2048 + r], gval);
            }
            __syncthreads();
        }
    }
    VMCNT0();
    if (tid == 0) postmk(&mk[SLOTG + b * 16]);

    // ======================= watchers: aggregate slotC + slotG =============
    if (b >= 88 && b < 120) {
        const int w = b - 88;
        const int cfrom = w * 29, cto = (cfrom + 29 < 912) ? cfrom + 29 : 912;
        if (tid < cto - cfrom) {
            for (int it = 0; it < BOUND; ++it) {
                if (peekmk(&mk[SLOTC + (cfrom + tid) * 16]) == MAGIC) break;
                __builtin_amdgcn_s_sleep(8);
            }
        } else if (tid >= 64 && tid < 96) {
            for (int it = 0; it < BOUND; ++it) {
                if (peekmk(&mk[SLOTG + (w * 32 + tid - 64) * 16]) == MAGIC) break;
                __builtin_amdgcn_s_sleep(8);
            }
        }
        __syncthreads();
        if (tid == 0) { postmk(&mk[SUPC + w * 16]); postmk(&mk[SUPG + w * 16]); }
    }

    // ======================= phase 3: GRU (all blocks, 2 cols) =============
    {
        const int t = tid;
        if (t < 32) {
            for (int it = 0; it < BOUND; ++it) {
                if (peekmk(&mk[SUPC + t * 16]) == MAGIC) break;
                __builtin_amdgcn_s_sleep(8);
            }
        } else if (t >= 64 && t < 96) {
            for (int it = 0; it < BOUND; ++it) {
                if (peekmk(&mk[SUPG + (t - 64) * 16]) == MAGIC) break;
                __builtin_amdgcn_s_sleep(8);
            }
        }
        __syncthreads();
    }
    {
        unsigned long long* sh64 = reinterpret_cast<unsigned long long*>(sh);
        const unsigned long long* g64 =
            reinterpret_cast<const unsigned long long*>(grep + (b & (NREP - 1)) * 2048);
        for (int i = tid; i < H / 2; i += 256) sh64[i] = cload64(&g64[i]);
    }
    __syncthreads();
    {
        const float4* g4 = reinterpret_cast<const float4*>(sh);
        #pragma unroll
        for (int cc = 0; cc < 2; ++cc) {
            const int col = b * 2 + cc;
            const float4* W0 = reinterpret_cast<const float4*>(w_ih + (size_t)col * H);
            const float4* W1 = reinterpret_cast<const float4*>(w_ih + (size_t)(col + H) * H);
            const float4* W2 = reinterpret_cast<const float4*>(w_ih + (size_t)(col + 2 * H) * H);
            const float4 gv0 = g4[tid], gv1 = g4[tid + 256];
            float ar = dot4(W0[tid], gv0, 0.f); ar = dot4(W0[tid + 256], gv1, ar);
            float az = dot4(W1[tid], gv0, 0.f); az = dot4(W1[tid + 256], gv1, az);
            float an = dot4(W2[tid], gv0, 0.f); an = dot4(W2[tid + 256], gv1, an);
            ar = wsum(ar); az = wsum(az); an = wsum(an);
            if (lane == 0) { p3[wv][0] = ar; p3[wv][1] = az; p3[wv][2] = an; }
            __syncthreads();
            if (tid == 0) {
                const float ir  = p3[0][0] + p3[1][0] + p3[2][0] + p3[3][0] + b_ih[col];
                const float iz  = p3[0][1] + p3[1][1] + p3[2][1] + p3[3][1] + b_ih[col + H];
                const float in_ = p3[0][2] + p3[1][2] + p3[2][2] + p3[3][2] + b_ih[col + 2 * H];
                const float r = 1.f / (1.f + expf(-(ir + cload(&gh[col]))));
                const float z = 1.f / (1.f + expf(-(iz + cload(&gh[col + H]))));
                const float n = tanhf(in_ + r * cload(&gh[col + 2 * H]));
                const float hnew = (1.f - z) * n + z * hidden[col];
                out[col] = hnew;
                out[H + col] = hnew;
            }
            __syncthreads();
        }
    }
}

extern "C" void kernel_launch(void* const* d_in, const int* in_sizes, int n_in,
                              void* d_out, int out_size, void* d_ws, size_t ws_size,
                              hipStream_t stream)
{
    const float* input  = (const float*)d_in[0];
    const float* hidden = (const float*)d_in[1];
    const float* enc    = (const float*)d_in[2];
    const float* attn_W = (const float*)d_in[3];
    const float* attn_b = (const float*)d_in[4];
    const float* comb_W = (const float*)d_in[5];
    const float* comb_b = (const float*)d_in[6];
    const float* w_ih   = (const float*)d_in[7];
    const float* w_hh   = (const float*)d_in[8];
    const float* b_ih   = (const float*)d_in[9];
    const float* b_hh   = (const float*)d_in[10];
    float* out = (float*)d_out;
    float* ws  = (float*)d_ws;

    fused_decoder<<<NB, 256, 0, stream>>>(
        input, hidden, enc, attn_W, attn_b, comb_W, comb_b,
        w_ih, w_hh, b_ih, b_hh, out, ws);
}